// Round 1
// baseline (564.866 us; speedup 1.0000x reference)
//
#include <hip/hip_runtime.h>

#define EPS 1e-4f
#define D 64
#define NCASES 8
#define ROWS_PER_BLOCK 128
#define ROWS_PER_WAVE 32  // 4 waves * 32 rows = 128

// ---------------------------------------------------------------------------
// Kernel 1: precompute W_sum (64x64) and b_sum (64) into workspace.
// ws layout: [0..4095] = W_sum (row-major i*64+j), [4096..4159] = b_sum.
// ---------------------------------------------------------------------------
__global__ void prep_sums(const float* __restrict__ W, const float* __restrict__ b,
                          float* __restrict__ ws) {
  int idx = blockIdx.x * blockDim.x + threadIdx.x;
  if (idx < D * D) {
    float s = 0.f;
#pragma unroll
    for (int c = 0; c < NCASES; ++c) s += W[c * D * D + idx];
    ws[idx] = s;
  } else if (idx < D * D + D) {
    int j = idx - D * D;
    float s = 0.f;
#pragma unroll
    for (int c = 0; c < NCASES; ++c) s += b[c * D + j];
    ws[idx] = s;
  }
}

// 16-byte async global->LDS copy. LDS dest is wave-uniform base (HW adds
// lane*16); global src is per-lane.
__device__ __forceinline__ void async_copy16(const void* g, void* l) {
  __builtin_amdgcn_global_load_lds(
      (const __attribute__((address_space(1))) unsigned int*)g,
      (__attribute__((address_space(3))) unsigned int*)l, 16, 0, 0);
}

// ---------------------------------------------------------------------------
// Kernel 2: lane j owns output column j; Wsum column resident in VGPRs.
// Block stages 128 rows of x (32 KB) + presence (4 KB) into LDS async,
// each wave computes 32 rows: out[r][j] = bsum[j] + dot(x[r,:], Wsum[:,j]),
// minus rare inactive-case corrections (wave-uniform branch).
// ---------------------------------------------------------------------------
__global__ __launch_bounds__(256, 4) void guarded_layer(
    const float* __restrict__ x, const float* __restrict__ presence,
    const float* __restrict__ W, const float* __restrict__ b,
    const float* __restrict__ Wsum, const float* __restrict__ bsum,
    float* __restrict__ out, int N) {
  __shared__ float xs[ROWS_PER_BLOCK * D];       // 32 KB, linear = global layout
  __shared__ float ps[ROWS_PER_BLOCK * NCASES];  // 4 KB, linear = global layout

  const int tid = threadIdx.x;
  const int lane = tid & 63;
  const int wave = tid >> 6;
  const long long r0 = (long long)blockIdx.x * ROWS_PER_BLOCK;

  // ---- async stage: x tile (32 chunks of 1 KB), presence tile (4 chunks) ----
  {
    const size_t x_base = (size_t)r0 * D * 4;
    const size_t x_last = (size_t)N * D * 4 - 16;  // clamp keeps src in-bounds
    const size_t p_base = (size_t)r0 * NCASES * 4;
    const size_t p_last = (size_t)N * NCASES * 4 - 16;
#pragma unroll
    for (int c = 0; c < 8; ++c) {
      const int chunk = wave * 8 + c;
      size_t g = x_base + (size_t)chunk * 1024 + (size_t)lane * 16;
      if (g > x_last) g = x_last;  // OOB rows: duplicate last row, never stored
      async_copy16((const char*)x + g, (char*)xs + chunk * 1024);
    }
    {
      size_t g = p_base + (size_t)wave * 1024 + (size_t)lane * 16;
      if (g > p_last) g = p_last;
      async_copy16((const char*)presence + g, (char*)ps + wave * 1024);
    }
  }

  // ---- resident Wsum column + bsum for this lane (L2-hot, 16 KB total) ----
  float wcol[D];
#pragma unroll
  for (int i = 0; i < D; ++i) wcol[i] = Wsum[i * D + lane];
  float bs = bsum[lane];

  __syncthreads();  // drains vmcnt(0): staging + wcol loads complete

  const float4* xs4 = reinterpret_cast<const float4*>(xs);
  const float4* ps4 = reinterpret_cast<const float4*>(ps);

#pragma unroll 1
  for (int k = 0; k < ROWS_PER_WAVE; ++k) {
    const int rl = wave * ROWS_PER_WAVE + k;
    const long long row = r0 + rl;
    const float4* xr = xs4 + rl * 16;  // 16 broadcast ds_read_b128

    float4 p0 = ps4[rl * 2 + 0];
    float4 p1 = ps4[rl * 2 + 1];

    float a0 = 0.f, a1 = 0.f, a2 = 0.f, a3 = 0.f;
#pragma unroll
    for (int c = 0; c < 16; ++c) {
      float4 xc = xr[c];
      a0 = fmaf(xc.x, wcol[4 * c + 0], a0);
      a1 = fmaf(xc.y, wcol[4 * c + 1], a1);
      a2 = fmaf(xc.z, wcol[4 * c + 2], a2);
      a3 = fmaf(xc.w, wcol[4 * c + 3], a3);
    }
    float r = ((a0 + a1) + (a2 + a3)) + bs;

    // presence values are identical across lanes -> branch is wave-uniform
    float pmin = fminf(fminf(fminf(p0.x, p0.y), fminf(p0.z, p0.w)),
                       fminf(fminf(p1.x, p1.y), fminf(p1.z, p1.w)));
    if (!(pmin > EPS)) {
      // Rare (~8e-4 of rows): subtract inactive-case contributions.
#pragma unroll 1
      for (int c = 0; c < NCASES; ++c) {
        float pc = ps[rl * NCASES + c];
        if (!(pc > EPS)) {
          const float* Wc = W + c * D * D;
          float s0 = 0.f, s1 = 0.f, s2 = 0.f, s3 = 0.f;
#pragma unroll
          for (int q = 0; q < 16; ++q) {
            float4 xc = xr[q];
            s0 = fmaf(xc.x, Wc[(4 * q + 0) * D + lane], s0);
            s1 = fmaf(xc.y, Wc[(4 * q + 1) * D + lane], s1);
            s2 = fmaf(xc.z, Wc[(4 * q + 2) * D + lane], s2);
            s3 = fmaf(xc.w, Wc[(4 * q + 3) * D + lane], s3);
          }
          r -= ((s0 + s1) + (s2 + s3)) + b[c * D + lane];
        }
      }
    }

    if (row < N) {
      // coalesced 256 B per wave-instr; streaming -> nontemporal
      __builtin_nontemporal_store(r, out + (size_t)row * D + lane);
    }
  }
}

extern "C" void kernel_launch(void* const* d_in, const int* in_sizes, int n_in,
                              void* d_out, int out_size, void* d_ws, size_t ws_size,
                              hipStream_t stream) {
  const float* x = (const float*)d_in[0];
  const float* presence = (const float*)d_in[1];
  const float* W = (const float*)d_in[2];
  const float* b = (const float*)d_in[3];
  float* out = (float*)d_out;
  float* ws = (float*)d_ws;

  int N = in_sizes[0] / D;

  prep_sums<<<(D * D + D + 255) / 256, 256, 0, stream>>>(W, b, ws);

  int nblocks = (N + ROWS_PER_BLOCK - 1) / ROWS_PER_BLOCK;
  guarded_layer<<<nblocks, 256, 0, stream>>>(
      x, presence, W, b, ws, ws + D * D, out, N);
}